// Round 7
// baseline (75.131 us; speedup 1.0000x reference)
//
#include <hip/hip_runtime.h>
#include <math.h>

#define NT 256
#define L_LEN 720
#define NROWS (64 * 321)        // 20544
#define CHUNKS_PER_ROW 180      // 720 / 4
#define NCHUNK (NROWS * CHUNKS_PER_ROW)
#define WM_STRIDE 12            // floats per row in ws: Wm[9], Bm, pad, pad

#define LOG2E 1.4426950408889634f
#define LN2   0.6931471805599453f

// ---------------------------------------------------------------------------
// Kernel 1: per-row entropy -> MLP -> softmax -> merged 9-tap conv weights.
// One wave per row, 4 independent waves per block, no LDS, no barriers.
// Live set is tiny (xw dies after the S/T loop) -> allocator can't sabotage.
// ---------------------------------------------------------------------------
__global__ __launch_bounds__(NT, 8) void ent_kernel(
    const float* __restrict__ x,
    const float* __restrict__ cw0, const float* __restrict__ cb0,
    const float* __restrict__ cw1, const float* __restrict__ cb1,
    const float* __restrict__ cw2, const float* __restrict__ cb2,
    const float* __restrict__ cw3, const float* __restrict__ cb3,
    const float* __restrict__ W1, const float* __restrict__ b1,
    const float* __restrict__ W2, const float* __restrict__ b2,
    float* __restrict__ wm)
{
    const int lane = threadIdx.x & 63;
    const int wid  = threadIdx.x >> 6;
    const int row  = blockIdx.x * 4 + wid;

    const float* __restrict__ xr = x + (size_t)row * L_LEN;

    // conv weights: uniform addresses -> scalar loads -> SGPRs
    const float* cws[4] = {cw0, cw1, cw2, cw3};
    const float* cbs[4] = {cb0, cb1, cb2, cb3};
    float w[4][9], bias[4];
#pragma unroll
    for (int s = 0; s < 4; ++s) {
        const int k = 3 + 2 * s;
        bias[s] = cbs[s][0];
#pragma unroll
        for (int t = 0; t < 9; ++t) w[s][t] = (t < k) ? cws[s][t] : 0.0f;
    }

    // lane t owns elements 12t .. 12t+11 ; lanes 60..63 idle (60*12 == 720)
    const bool active = lane < 60;

    float S[4]  = {0.f, 0.f, 0.f, 0.f};   // sum 2^u   (= sum e^f)
    float Tu[4] = {0.f, 0.f, 0.f, 0.f};   // sum u*2^u (T = ln2 * Tu)

    if (active) {
        const int e0 = 12 * lane - 4;
        float xw[20];
#pragma unroll
        for (int q = 0; q < 5; ++q) {
            int e = e0 + 4 * q;
            e = (e < 0) ? 0 : ((e > L_LEN - 4) ? (L_LEN - 4) : e);  // 16B-aligned
            float4 v = *(const float4*)(xr + e);
            xw[4 * q + 0] = v.x; xw[4 * q + 1] = v.y;
            xw[4 * q + 2] = v.z; xw[4 * q + 3] = v.w;
        }
        if (lane == 0)  { xw[0] = 0.f; xw[1] = 0.f; xw[2] = 0.f; xw[3] = 0.f; }
        if (lane == 59) { xw[16] = 0.f; xw[17] = 0.f; xw[18] = 0.f; xw[19] = 0.f; }

        // fused: conv -> u = f*log2e -> 2^u -> accumulate S, Tu. Nothing kept.
#pragma unroll
        for (int e = 0; e < 12; ++e) {
#pragma unroll
            for (int s = 0; s < 4; ++s) {
                const int k = 3 + 2 * s;
                const int off = 3 - s;          // 4 - k/2
                float acc = bias[s];
#pragma unroll
                for (int u = 0; u < k; ++u)
                    acc = fmaf(w[s][u], xw[e + off + u], acc);
                float uu = acc * LOG2E;
                float ev = __builtin_amdgcn_exp2f(uu);
                S[s]  += ev;
                Tu[s]  = fmaf(uu, ev, Tu[s]);
            }
        }
    }

    // wave-wide reduce (8 independent chains)
#pragma unroll
    for (int s = 0; s < 4; ++s) {
#pragma unroll
        for (int off = 32; off; off >>= 1) {
            S[s]  += __shfl_xor(S[s],  off);
            Tu[s] += __shfl_xor(Tu[s], off);
        }
    }

    // entropy = ln2 * (log2 S - Tu/S)   (shift-free, fp32-safe for f~N(0,1))
    float ent[4];
#pragma unroll
    for (int s = 0; s < 4; ++s)
        ent[s] = LN2 * (__builtin_amdgcn_logf(S[s])
                        - Tu[s] * __builtin_amdgcn_rcpf(S[s]));

    // MLP: hidden unit per lane (mod 32); logits via 32-lane shuffle reduce
    const int hidx = lane & 31;
    float h = b1[hidx];
#pragma unroll
    for (int s = 0; s < 4; ++s) h = fmaf(ent[s], W1[s * 32 + hidx], h);
    h = fmaxf(h, 0.0f);

    const float4 w2v = ((const float4*)W2)[hidx];
    float lg[4] = {h * w2v.x, h * w2v.y, h * w2v.z, h * w2v.w};
#pragma unroll
    for (int c = 0; c < 4; ++c) {
#pragma unroll
        for (int off = 16; off; off >>= 1)
            lg[c] += __shfl_xor(lg[c], off);
    }
    lg[0] += b2[0]; lg[1] += b2[1]; lg[2] += b2[2]; lg[3] += b2[3];

    float m = fmaxf(fmaxf(lg[0], lg[1]), fmaxf(lg[2], lg[3]));
    float e0w = __expf(lg[0] - m), e1w = __expf(lg[1] - m);
    float e2w = __expf(lg[2] - m), e3w = __expf(lg[3] - m);
    float inv = 1.0f / (e0w + e1w + e2w + e3w);
    const float wgt[4] = {e0w * inv, e1w * inv, e2w * inv, e3w * inv};

    // merge the 4 kernels: Wm[j] = sum_s wgt[s]*w[s][j-off_s], Bm = sum wgt*bias
    float Wm[9] = {0,0,0,0,0,0,0,0,0};
    float Bm = 0.f;
#pragma unroll
    for (int s = 0; s < 4; ++s) {
        const int k = 3 + 2 * s;
        const int off = 3 - s;
#pragma unroll
        for (int u = 0; u < k; ++u)
            Wm[off + u] = fmaf(wgt[s], w[s][u], Wm[off + u]);
        Bm = fmaf(wgt[s], bias[s], Bm);
    }

    if (lane == 0) {
        float* __restrict__ dst = wm + (size_t)row * WM_STRIDE;
        float4 a = {Wm[0], Wm[1], Wm[2], Wm[3]};
        float4 b = {Wm[4], Wm[5], Wm[6], Wm[7]};
        float2 c = {Wm[8], Bm};
        *(float4*)(dst)     = a;
        *(float4*)(dst + 4) = b;
        *(float2*)(dst + 8) = c;
    }
}

// ---------------------------------------------------------------------------
// Kernel 2: pure streaming. One thread = one float4 of output; merged 9-tap
// conv from 3 overlapping float4 x-loads + the row's weights from ws (L2-hot).
// ---------------------------------------------------------------------------
__global__ __launch_bounds__(NT) void out_kernel(
    const float* __restrict__ x,
    const float* __restrict__ wm,
    float* __restrict__ out)
{
    const int c = blockIdx.x * NT + threadIdx.x;      // chunk id, < NCHUNK
    const int r  = c / CHUNKS_PER_ROW;                // row (magic-mul div)
    const int j4 = (c - r * CHUNKS_PER_ROW) * 4;      // first output element

    const float* __restrict__ xr = x + (size_t)r * L_LEN;
    const float* __restrict__ wr = wm + (size_t)r * WM_STRIDE;

    const float4 wa = *(const float4*)(wr);           // Wm0..3
    const float4 wb = *(const float4*)(wr + 4);       // Wm4..7
    const float2 wc = *(const float2*)(wr + 8);       // Wm8, Bm
    const float W[9] = {wa.x, wa.y, wa.z, wa.w, wb.x, wb.y, wb.z, wb.w, wc.x};
    const float Bm = wc.y;

    // window x[j4-4 .. j4+7]
    float xv[12];
    if (j4 >= 4 && j4 <= L_LEN - 8) {                 // interior fast path
        float4 A = *(const float4*)(xr + j4 - 4);
        float4 B = *(const float4*)(xr + j4);
        float4 C = *(const float4*)(xr + j4 + 4);
        xv[0] = A.x; xv[1] = A.y; xv[2]  = A.z; xv[3]  = A.w;
        xv[4] = B.x; xv[5] = B.y; xv[6]  = B.z; xv[7]  = B.w;
        xv[8] = C.x; xv[9] = C.y; xv[10] = C.z; xv[11] = C.w;
    } else {                                          // row edges: zero-fill
#pragma unroll
        for (int t = 0; t < 12; ++t) {
            const int e = j4 - 4 + t;
            xv[t] = (e >= 0 && e < L_LEN) ? xr[e] : 0.0f;
        }
    }

    float4 o;
#pragma unroll
    for (int c0 = 0; c0 < 4; ++c0) {
        float acc = Bm;
#pragma unroll
        for (int d = 0; d < 9; ++d)
            acc = fmaf(W[d], xv[c0 + d], acc);
        ((float*)&o)[c0] = acc;
    }
    *(float4*)(out + (size_t)r * L_LEN + j4) = o;
}

extern "C" void kernel_launch(void* const* d_in, const int* in_sizes, int n_in,
                              void* d_out, int out_size, void* d_ws, size_t ws_size,
                              hipStream_t stream) {
    const float* xp  = (const float*)d_in[0];
    const float* cw0 = (const float*)d_in[1];
    const float* cb0 = (const float*)d_in[2];
    const float* cw1 = (const float*)d_in[3];
    const float* cb1 = (const float*)d_in[4];
    const float* cw2 = (const float*)d_in[5];
    const float* cb2 = (const float*)d_in[6];
    const float* cw3 = (const float*)d_in[7];
    const float* cb3 = (const float*)d_in[8];
    const float* W1  = (const float*)d_in[9];
    const float* b1  = (const float*)d_in[10];
    const float* W2  = (const float*)d_in[11];
    const float* b2  = (const float*)d_in[12];
    float* outp = (float*)d_out;
    float* wm   = (float*)d_ws;    // NROWS * WM_STRIDE floats = 986 KB

    ent_kernel<<<NROWS / 4, NT, 0, stream>>>(xp, cw0, cb0, cw1, cb1, cw2, cb2,
                                             cw3, cb3, W1, b1, W2, b2, wm);
    out_kernel<<<NCHUNK / NT, NT, 0, stream>>>(xp, wm, outp);
}

// Round 8
// 49.308 us; speedup vs baseline: 1.5237x; 1.5237x over previous
//
#include <hip/hip_runtime.h>
#include <math.h>

#define NT 256
#define L_LEN 720
#define NROWS (64 * 321)        // 20544
#define CHUNKS_PER_ROW 180      // 720 / 4
#define NCHUNK (NROWS * CHUNKS_PER_ROW)
#define WM_STRIDE 12            // floats per row in ws: Wm[9], Bm, pad, pad

#define LOG2E 1.4426950408889634f
#define LN2   0.6931471805599453f

// ---------------------------------------------------------------------------
// Kernel 1: per-row entropy -> MLP -> softmax -> merged 9-tap conv weights.
// One wave per row, 4 independent waves per block, no LDS, no barriers.
// __launch_bounds__(256,4) => 128-VGPR budget: ~2x the honest live set, so
// the allocator has NO reason to spill (R7: budget 64 -> 150 MB scratch storm)
// or rematerialize (R3/R5).
// ---------------------------------------------------------------------------
__global__ __launch_bounds__(NT, 4) void ent_kernel(
    const float* __restrict__ x,
    const float* __restrict__ cw0, const float* __restrict__ cb0,
    const float* __restrict__ cw1, const float* __restrict__ cb1,
    const float* __restrict__ cw2, const float* __restrict__ cb2,
    const float* __restrict__ cw3, const float* __restrict__ cb3,
    const float* __restrict__ W1, const float* __restrict__ b1,
    const float* __restrict__ W2, const float* __restrict__ b2,
    float* __restrict__ wm)
{
    const int lane = threadIdx.x & 63;
    const int wid  = threadIdx.x >> 6;
    const int row  = blockIdx.x * 4 + wid;

    const float* __restrict__ xr = x + (size_t)row * L_LEN;

    // conv weights: uniform addresses -> scalar loads -> SGPRs
    const float* cws[4] = {cw0, cw1, cw2, cw3};
    const float* cbs[4] = {cb0, cb1, cb2, cb3};
    float w[4][9], bias[4];
#pragma unroll
    for (int s = 0; s < 4; ++s) {
        const int k = 3 + 2 * s;
        bias[s] = cbs[s][0];
#pragma unroll
        for (int t = 0; t < 9; ++t) w[s][t] = (t < k) ? cws[s][t] : 0.0f;
    }

    // lane t owns elements 12t .. 12t+11 ; lanes 60..63 idle (60*12 == 720)
    const bool active = lane < 60;

    float S[4]  = {0.f, 0.f, 0.f, 0.f};   // sum 2^u   (= sum e^f)
    float Tu[4] = {0.f, 0.f, 0.f, 0.f};   // sum u*2^u (T = ln2 * Tu)

    if (active) {
        const int e0 = 12 * lane - 4;
        float xw[20];
#pragma unroll
        for (int q = 0; q < 5; ++q) {
            int e = e0 + 4 * q;
            e = (e < 0) ? 0 : ((e > L_LEN - 4) ? (L_LEN - 4) : e);  // 16B-aligned
            float4 v = *(const float4*)(xr + e);
            xw[4 * q + 0] = v.x; xw[4 * q + 1] = v.y;
            xw[4 * q + 2] = v.z; xw[4 * q + 3] = v.w;
        }
        if (lane == 0)  { xw[0] = 0.f; xw[1] = 0.f; xw[2] = 0.f; xw[3] = 0.f; }
        if (lane == 59) { xw[16] = 0.f; xw[17] = 0.f; xw[18] = 0.f; xw[19] = 0.f; }

        // Pin the window: loaded exactly once, no remat/re-fetch.
#pragma unroll
        for (int t = 0; t < 20; ++t) asm volatile("" : "+v"(xw[t]));

        // fused: conv -> u = f*log2e -> 2^u -> accumulate S, Tu. Nothing kept.
#pragma unroll
        for (int e = 0; e < 12; ++e) {
#pragma unroll
            for (int s = 0; s < 4; ++s) {
                const int k = 3 + 2 * s;
                const int off = 3 - s;          // 4 - k/2
                float acc = bias[s];
#pragma unroll
                for (int u = 0; u < k; ++u)
                    acc = fmaf(w[s][u], xw[e + off + u], acc);
                float uu = acc * LOG2E;
                float ev = __builtin_amdgcn_exp2f(uu);
                S[s]  += ev;
                Tu[s]  = fmaf(uu, ev, Tu[s]);
            }
        }
    }

    // wave-wide reduce (8 independent chains)
#pragma unroll
    for (int s = 0; s < 4; ++s) {
#pragma unroll
        for (int off = 32; off; off >>= 1) {
            S[s]  += __shfl_xor(S[s],  off);
            Tu[s] += __shfl_xor(Tu[s], off);
        }
    }

    // entropy = ln2 * (log2 S - Tu/S)   (shift-free, fp32-safe for f~N(0,1))
    float ent[4];
#pragma unroll
    for (int s = 0; s < 4; ++s)
        ent[s] = LN2 * (__builtin_amdgcn_logf(S[s])
                        - Tu[s] * __builtin_amdgcn_rcpf(S[s]));

    // MLP: hidden unit per lane (mod 32); logits via 32-lane shuffle reduce
    const int hidx = lane & 31;
    float h = b1[hidx];
#pragma unroll
    for (int s = 0; s < 4; ++s) h = fmaf(ent[s], W1[s * 32 + hidx], h);
    h = fmaxf(h, 0.0f);

    const float4 w2v = ((const float4*)W2)[hidx];
    float lg[4] = {h * w2v.x, h * w2v.y, h * w2v.z, h * w2v.w};
#pragma unroll
    for (int c = 0; c < 4; ++c) {
#pragma unroll
        for (int off = 16; off; off >>= 1)
            lg[c] += __shfl_xor(lg[c], off);
    }
    lg[0] += b2[0]; lg[1] += b2[1]; lg[2] += b2[2]; lg[3] += b2[3];

    float m = fmaxf(fmaxf(lg[0], lg[1]), fmaxf(lg[2], lg[3]));
    float e0w = __expf(lg[0] - m), e1w = __expf(lg[1] - m);
    float e2w = __expf(lg[2] - m), e3w = __expf(lg[3] - m);
    float inv = 1.0f / (e0w + e1w + e2w + e3w);
    const float wgt[4] = {e0w * inv, e1w * inv, e2w * inv, e3w * inv};

    // merge the 4 kernels: Wm[j] = sum_s wgt[s]*w[s][j-off_s], Bm = sum wgt*bias
    float Wm[9] = {0,0,0,0,0,0,0,0,0};
    float Bm = 0.f;
#pragma unroll
    for (int s = 0; s < 4; ++s) {
        const int k = 3 + 2 * s;
        const int off = 3 - s;
#pragma unroll
        for (int u = 0; u < k; ++u)
            Wm[off + u] = fmaf(wgt[s], w[s][u], Wm[off + u]);
        Bm = fmaf(wgt[s], bias[s], Bm);
    }

    if (lane == 0) {
        float* __restrict__ dst = wm + (size_t)row * WM_STRIDE;
        float4 a = {Wm[0], Wm[1], Wm[2], Wm[3]};
        float4 b = {Wm[4], Wm[5], Wm[6], Wm[7]};
        float2 c = {Wm[8], Bm};
        *(float4*)(dst)     = a;
        *(float4*)(dst + 4) = b;
        *(float2*)(dst + 8) = c;
    }
}

// ---------------------------------------------------------------------------
// Kernel 2: pure streaming. One thread = one float4 of output; merged 9-tap
// conv from 3 overlapping float4 x-loads + the row's weights from ws (L2-hot).
// Measured ~7 us in R7 -- unchanged.
// ---------------------------------------------------------------------------
__global__ __launch_bounds__(NT) void out_kernel(
    const float* __restrict__ x,
    const float* __restrict__ wm,
    float* __restrict__ out)
{
    const int c = blockIdx.x * NT + threadIdx.x;      // chunk id, < NCHUNK
    const int r  = c / CHUNKS_PER_ROW;                // row
    const int j4 = (c - r * CHUNKS_PER_ROW) * 4;      // first output element

    const float* __restrict__ xr = x + (size_t)r * L_LEN;
    const float* __restrict__ wr = wm + (size_t)r * WM_STRIDE;

    const float4 wa = *(const float4*)(wr);           // Wm0..3
    const float4 wb = *(const float4*)(wr + 4);       // Wm4..7
    const float2 wc = *(const float2*)(wr + 8);       // Wm8, Bm
    const float W[9] = {wa.x, wa.y, wa.z, wa.w, wb.x, wb.y, wb.z, wb.w, wc.x};
    const float Bm = wc.y;

    // window x[j4-4 .. j4+7]
    float xv[12];
    if (j4 >= 4 && j4 <= L_LEN - 8) {                 // interior fast path
        float4 A = *(const float4*)(xr + j4 - 4);
        float4 B = *(const float4*)(xr + j4);
        float4 C = *(const float4*)(xr + j4 + 4);
        xv[0] = A.x; xv[1] = A.y; xv[2]  = A.z; xv[3]  = A.w;
        xv[4] = B.x; xv[5] = B.y; xv[6]  = B.z; xv[7]  = B.w;
        xv[8] = C.x; xv[9] = C.y; xv[10] = C.z; xv[11] = C.w;
    } else {                                          // row edges: zero-fill
#pragma unroll
        for (int t = 0; t < 12; ++t) {
            const int e = j4 - 4 + t;
            xv[t] = (e >= 0 && e < L_LEN) ? xr[e] : 0.0f;
        }
    }

    float4 o;
#pragma unroll
    for (int c0 = 0; c0 < 4; ++c0) {
        float acc = Bm;
#pragma unroll
        for (int d = 0; d < 9; ++d)
            acc = fmaf(W[d], xv[c0 + d], acc);
        ((float*)&o)[c0] = acc;
    }
    *(float4*)(out + (size_t)r * L_LEN + j4) = o;
}

extern "C" void kernel_launch(void* const* d_in, const int* in_sizes, int n_in,
                              void* d_out, int out_size, void* d_ws, size_t ws_size,
                              hipStream_t stream) {
    const float* xp  = (const float*)d_in[0];
    const float* cw0 = (const float*)d_in[1];
    const float* cb0 = (const float*)d_in[2];
    const float* cw1 = (const float*)d_in[3];
    const float* cb1 = (const float*)d_in[4];
    const float* cw2 = (const float*)d_in[5];
    const float* cb2 = (const float*)d_in[6];
    const float* cw3 = (const float*)d_in[7];
    const float* cb3 = (const float*)d_in[8];
    const float* W1  = (const float*)d_in[9];
    const float* b1  = (const float*)d_in[10];
    const float* W2  = (const float*)d_in[11];
    const float* b2  = (const float*)d_in[12];
    float* outp = (float*)d_out;
    float* wm   = (float*)d_ws;    // NROWS * WM_STRIDE floats = 986 KB

    ent_kernel<<<NROWS / 4, NT, 0, stream>>>(xp, cw0, cb0, cw1, cb1, cw2, cb2,
                                             cw3, cb3, W1, b1, W2, b2, wm);
    out_kernel<<<NCHUNK / NT, NT, 0, stream>>>(xp, wm, outp);
}